// Round 13
// baseline (501.489 us; speedup 1.0000x reference)
//
#include <hip/hip_runtime.h>
#include <hip/hip_bf16.h>

constexpr int N    = 100000;
constexpr int E    = 1600000;
constexpr int NSG2 = 20000;
constexpr int NSG  = 2000;
constexpr int NG   = 64;
constexpr int D    = 64;
constexpr int L    = 5;

constexpr int CB    = (N + 255) / 256;    // 391 coarse buckets (256 nodes each)
constexpr int NSTR  = 8;                  // stripes (≈XCDs)
constexpr int SCAP2 = 768;                // per (stripe,bucket) cap: mean 512, +11 sigma
constexpr int NBIN  = 48;                 // degree bins for balance sort

typedef __attribute__((ext_vector_type(8))) short short8v;
typedef __attribute__((ext_vector_type(4))) float f32x4;

__device__ __forceinline__ float sigm(float x) { return 1.0f / (1.0f + expf(-x)); }
__device__ __forceinline__ float elu(float x)  { return x > 0.0f ? x : (expf(x) - 1.0f); }

__device__ __forceinline__ unsigned short f2b(float f) {
    union { float f; unsigned u; } x; x.f = f;
    unsigned r = (x.u + 0x7FFFu + ((x.u >> 16) & 1u)) >> 16;   // RNE
    return (unsigned short)r;
}
__device__ __forceinline__ float b2f(unsigned short h) {
    union { unsigned u; float f; } x; x.u = (unsigned)h << 16;
    return x.f;
}

// ---- WihP[l] = conv_W[l] @ gru_Wih[l]  (64x64 @ 64x192) ----
__global__ __launch_bounds__(256) void prep_kernel(const float* __restrict__ convW,
                                                   const float* __restrict__ Wih,
                                                   float* __restrict__ WihP) {
    int idx = blockIdx.x * 256 + threadIdx.x;   // L*64*192 = 61440
    if (idx >= L * 64 * 192) return;
    int l = idx / (64 * 192);
    int rem = idx % (64 * 192);
    int i = rem / 192, j = rem % 192;
    const float* W  = convW + l * 64 * 64;
    const float* Wi = Wih  + l * 64 * 192;
    float acc = 0.0f;
    for (int t = 0; t < 64; ++t) acc = fmaf(W[i * 64 + t], Wi[t * 192 + j], acc);
    WihP[idx] = acc;
}

// ---- pack GRU weights into bf16 MFMA B-fragments ----
__global__ __launch_bounds__(256) void packg_kernel(const float* __restrict__ WihP,
                                                    const float* __restrict__ gWhh,
                                                    unsigned short* __restrict__ Wgpk) {
    int idx = blockIdx.x * 256 + threadIdx.x;
    if (idx >= L * 2 * 12 * 2 * 64) return;
    int lane = idx & 63;
    int r1 = idx >> 6;
    int t  = r1 & 1;
    int r2 = r1 >> 1;
    int nt = r2 % 12;
    int lm = r2 / 12;             // l*2+mat
    int mat = lm & 1, l = lm >> 1;
    const float* W = mat ? (gWhh + (size_t)l * 64 * 192) : (WihP + (size_t)l * 64 * 192);
    int n  = nt * 16 + (lane & 15);
    int k0 = t * 32 + (lane >> 4) * 8;
    short8v v;
#pragma unroll
    for (int j = 0; j < 8; ++j) v[j] = (short)f2b(W[(k0 + j) * 192 + n]);
    *(short8v*)(Wgpk + (size_t)idx * 8) = v;
}

// ---- pack transform weights ----
__global__ __launch_bounds__(256) void packt_kernel(const float* __restrict__ tW,
                                                    unsigned short* __restrict__ tWpk) {
    int idx = blockIdx.x * 256 + threadIdx.x;
    if (idx >= (L - 1) * 4 * 4 * 64) return;
    int lane = idx & 63;
    int r1 = idx >> 6;
    int t  = r1 & 3;
    int r2 = r1 >> 2;
    int nt = r2 & 3;
    int lm = r2 >> 2;
    const float* W = tW + (size_t)lm * 128 * 64;
    int n  = nt * 16 + (lane & 15);
    int k0 = t * 32 + (lane >> 4) * 8;
    short8v v;
#pragma unroll
    for (int j = 0; j < 8; ++j) v[j] = (short)f2b(W[(k0 + j) * 64 + n]);
    *(short8v*)(tWpk + (size_t)idx * 8) = v;
}

// ---- CSR A: scatter into 391 coarse buckets x 8 stripes ----
__global__ void csrA_kernel(const int* __restrict__ src, const int* __restrict__ dst,
                            int* __restrict__ bcnt, unsigned* __restrict__ tmp) {
    int stripe = blockIdx.x & (NSTR - 1);
    for (int e = blockIdx.x * blockDim.x + threadIdx.x; e < E; e += gridDim.x * blockDim.x) {
        int d = dst[e];
        int cell = stripe * CB + (d >> 8);
        int pos = atomicAdd(&bcnt[cell * 16], 1);   // 64B-strided counters
        if (pos < SCAP2)
            tmp[(size_t)cell * SCAP2 + pos] = ((unsigned)(d & 255) << 17) | (unsigned)src[e];
    }
}

// ---- CSR B: one block per coarse bucket; hist(256) -> scan -> rowptr + sorted col ----
__global__ __launch_bounds__(256) void csrB_kernel(const unsigned* __restrict__ tmp,
                                                   const int* __restrict__ bcnt,
                                                   int* __restrict__ rowptr,
                                                   int* __restrict__ col) {
    __shared__ int hist[256];
    __shared__ int scanb[256];
    __shared__ int cur[256];
    __shared__ int scnt[NSTR];
    __shared__ int red[4];
    int b = blockIdx.x, t = threadIdx.x;
    int lane = t & 63, wid = t >> 6;

    int myb = 0;
    for (int cb = t; cb < b; cb += 256) {
        int tot = 0;
#pragma unroll
        for (int s = 0; s < NSTR; ++s) tot += min(bcnt[(s * CB + cb) * 16], SCAP2);
        myb += tot;
    }
#pragma unroll
    for (int off = 32; off > 0; off >>= 1) myb += __shfl_down(myb, off, 64);
    if (lane == 0) red[wid] = myb;
    if (t < NSTR) scnt[t] = min(bcnt[(t * CB + b) * 16], SCAP2);
    hist[t] = 0;
    __syncthreads();
    int base = red[0] + red[1] + red[2] + red[3];

    for (int s = 0; s < NSTR; ++s)
        for (int i = t; i < scnt[s]; i += 256)
            atomicAdd(&hist[tmp[((size_t)s * CB + b) * SCAP2 + i] >> 17], 1);
    __syncthreads();

    scanb[t] = hist[t];
    __syncthreads();
    for (int off = 1; off < 256; off <<= 1) {
        int v = (t >= off) ? scanb[t - off] : 0;
        __syncthreads();
        scanb[t] += v;
        __syncthreads();
    }
    int excl = scanb[t] - hist[t];
    int node = b * 256 + t;
    if (node < N) rowptr[node] = base + excl;
    if (b == CB - 1 && t == 255) rowptr[N] = base + scanb[255];
    cur[t] = base + excl;
    __syncthreads();

    for (int s = 0; s < NSTR; ++s)
        for (int i = t; i < scnt[s]; i += 256) {
            unsigned rec = tmp[((size_t)s * CB + b) * SCAP2 + i];
            int pos = atomicAdd(&cur[rec >> 17], 1);
            col[pos] = (int)(rec & 0x1FFFFu);
        }
}

// ---- degree-balance permutation: counting sort by degree (3 tiny kernels) ----
__global__ __launch_bounds__(256) void degh_kernel(const int* __restrict__ rowptr,
                                                   int* __restrict__ bh) {
    __shared__ int h[NBIN];
    int b = blockIdx.x, t = threadIdx.x;
    if (t < NBIN) h[t] = 0;
    __syncthreads();
    int node = b * 256 + t;
    if (node < N) {
        int d = rowptr[node + 1] - rowptr[node];
        atomicAdd(&h[min(d, NBIN - 1)], 1);
    }
    __syncthreads();
    if (t < NBIN) bh[b * NBIN + t] = h[t];
}

__global__ __launch_bounds__(64) void degscan_kernel(int* __restrict__ bh) {
    __shared__ int gbase[NBIN + 1];
    int t = threadIdx.x;
    if (t < NBIN) {
        int run = 0;
        for (int b = 0; b < CB; ++b) {
            int v = bh[b * NBIN + t];
            bh[b * NBIN + t] = run;
            run += v;
        }
        gbase[t + 1] = run;
    }
    __syncthreads();
    if (t == 0) {
        gbase[0] = 0;
        for (int j = 1; j <= NBIN; ++j) gbase[j] += gbase[j - 1];
    }
    __syncthreads();
    if (t < NBIN) {
        int g = gbase[t];
        for (int b = 0; b < CB; ++b) bh[b * NBIN + t] += g;
    }
}

__global__ __launch_bounds__(256) void degscat_kernel(const int* __restrict__ rowptr,
                                                      const int* __restrict__ bh,
                                                      int* __restrict__ perm) {
    __shared__ int cur[NBIN];
    int b = blockIdx.x, t = threadIdx.x;
    if (t < NBIN) cur[t] = bh[b * NBIN + t];
    __syncthreads();
    int node = b * 256 + t;
    if (node < N) {
        int d = rowptr[node + 1] - rowptr[node];
        int pos = atomicAdd(&cur[min(d, NBIN - 1)], 1);
        perm[pos] = node;
    }
}

// ---- x0 = z_emb[0][z].sum(1) -> bf16 ----
__global__ __launch_bounds__(256) void embed_kernel(const int* __restrict__ z,
                                                    const float* __restrict__ zemb0,
                                                    unsigned short* __restrict__ xb) {
    int idx = blockIdx.x * 256 + threadIdx.x;  // N*16 float4 units
    if (idx >= N * 16) return;
    int n = idx >> 4, k4 = idx & 15;
    float4 e0 = ((const float4*)(zemb0 + (size_t)z[n * 2] * 64))[k4];
    float4 e1 = ((const float4*)(zemb0 + (size_t)z[n * 2 + 1] * 64))[k4];
    ushort4 b; b.x = f2b(e0.x + e1.x); b.y = f2b(e0.y + e1.y);
    b.z = f2b(e0.z + e1.z); b.w = f2b(e0.w + e1.w);
    ((ushort4*)xb)[idx] = b;
}

// ---- fused layer (degree-sorted node order via perm) ----
template<int HAS_T>
__global__ __launch_bounds__(256) void fused_kernel(const unsigned short* __restrict__ xb_in,
                                                    unsigned short* __restrict__ xb_out,
                                                    const int* __restrict__ rowptr,
                                                    const int* __restrict__ col,
                                                    const int* __restrict__ perm,
                                                    const unsigned short* __restrict__ Wgpk_l,
                                                    const float* __restrict__ bih,
                                                    const float* __restrict__ bhh,
                                                    const int* __restrict__ z,
                                                    const float* __restrict__ zemb_next,
                                                    const unsigned short* __restrict__ tWpk_next,
                                                    const float* __restrict__ tb_next,
                                                    const int* __restrict__ n2s2,
                                                    float* __restrict__ sg2) {
    __shared__ union {
        struct { unsigned short s[32][72]; unsigned short x[32][72]; } p1;  // 9216 B
        unsigned short a[32][136];                                          // 8704 B
    } u;
    __shared__ int pnodes[32];
    int tid = threadIdx.x;
    int node0 = blockIdx.x * 32;
    int lane = tid & 63, w = tid >> 6;

    if (tid < 32) pnodes[tid] = perm[node0 + tid];
    __syncthreads();

    // ---- phase 1: aggregate, 8/4/2/1-deep pipelined gather (equal-degree nodes) ----
    {
        int g8 = lane >> 3, cj = lane & 7;
        int nl = w * 8 + g8;
        int node = pnodes[nl];
        float4 ownx = ((const float4*)(xb_in + (size_t)node * 64))[cj];
        int beg = rowptr[node], end = rowptr[node + 1];
        float a[8] = {};
        const unsigned short* __restrict__ xbc = xb_in + cj * 8;
        int i = beg;
        for (; i + 8 <= end; i += 8) {
            int u0 = col[i],     u1 = col[i + 1], u2 = col[i + 2], u3 = col[i + 3];
            int u4 = col[i + 4], u5 = col[i + 5], u6 = col[i + 6], u7 = col[i + 7];
            short8v v0 = *(const short8v*)(xbc + (size_t)u0 * 64);
            short8v v1 = *(const short8v*)(xbc + (size_t)u1 * 64);
            short8v v2 = *(const short8v*)(xbc + (size_t)u2 * 64);
            short8v v3 = *(const short8v*)(xbc + (size_t)u3 * 64);
            short8v v4 = *(const short8v*)(xbc + (size_t)u4 * 64);
            short8v v5 = *(const short8v*)(xbc + (size_t)u5 * 64);
            short8v v6 = *(const short8v*)(xbc + (size_t)u6 * 64);
            short8v v7 = *(const short8v*)(xbc + (size_t)u7 * 64);
#pragma unroll
            for (int j = 0; j < 8; ++j)
                a[j] += ((b2f((unsigned short)v0[j]) + b2f((unsigned short)v1[j])) +
                         (b2f((unsigned short)v2[j]) + b2f((unsigned short)v3[j]))) +
                        ((b2f((unsigned short)v4[j]) + b2f((unsigned short)v5[j])) +
                         (b2f((unsigned short)v6[j]) + b2f((unsigned short)v7[j])));
        }
        for (; i + 4 <= end; i += 4) {
            int u0 = col[i], u1 = col[i + 1], u2 = col[i + 2], u3 = col[i + 3];
            short8v v0 = *(const short8v*)(xbc + (size_t)u0 * 64);
            short8v v1 = *(const short8v*)(xbc + (size_t)u1 * 64);
            short8v v2 = *(const short8v*)(xbc + (size_t)u2 * 64);
            short8v v3 = *(const short8v*)(xbc + (size_t)u3 * 64);
#pragma unroll
            for (int j = 0; j < 8; ++j)
                a[j] += (b2f((unsigned short)v0[j]) + b2f((unsigned short)v1[j])) +
                        (b2f((unsigned short)v2[j]) + b2f((unsigned short)v3[j]));
        }
        for (; i + 2 <= end; i += 2) {
            int u0 = col[i], u1 = col[i + 1];
            short8v v0 = *(const short8v*)(xbc + (size_t)u0 * 64);
            short8v v1 = *(const short8v*)(xbc + (size_t)u1 * 64);
#pragma unroll
            for (int j = 0; j < 8; ++j)
                a[j] += b2f((unsigned short)v0[j]) + b2f((unsigned short)v1[j]);
        }
        if (i < end) {
            short8v v = *(const short8v*)(xbc + (size_t)col[i] * 64);
#pragma unroll
            for (int j = 0; j < 8; ++j) a[j] += b2f((unsigned short)v[j]);
        }
        short8v r;
#pragma unroll
        for (int j = 0; j < 8; ++j) r[j] = (short)f2b(a[j]);
        *(short8v*)&u.p1.s[nl][cj * 8] = r;
        *(float4*)&u.p1.x[nl][cj * 8] = ownx;
    }
    __syncthreads();

    // ---- phase 2: GRU MFMA ----
    int lr = lane & 15, lg = lane >> 4;
    int ch = w * 16 + lr;
    short8v as_[2][2], ax_[2][2];
#pragma unroll
    for (int mt = 0; mt < 2; ++mt)
#pragma unroll
        for (int t = 0; t < 2; ++t) {
            int row = mt * 16 + lr, koff = t * 32 + lg * 8;
            as_[mt][t] = *(const short8v*)&u.p1.s[row][koff];
            ax_[mt][t] = *(const short8v*)&u.p1.x[row][koff];
        }
    float xres[2][4];
#pragma unroll
    for (int mt = 0; mt < 2; ++mt)
#pragma unroll
        for (int reg = 0; reg < 4; ++reg)
            xres[mt][reg] = b2f(u.p1.x[mt * 16 + lg * 4 + reg][ch]);
    if (HAS_T) __syncthreads();   // all p1 reads done before a-tile aliasing writes

    f32x4 accA[3][2] = {};
    f32x4 accB[3][2] = {};
#pragma unroll
    for (int g = 0; g < 3; ++g) {
        int nt = g * 4 + w;
#pragma unroll
        for (int t = 0; t < 2; ++t) {
            const unsigned short* pA = Wgpk_l + ((size_t)((0 * 12 + nt) * 2 + t) * 64 + lane) * 8;
            const unsigned short* pB = Wgpk_l + ((size_t)((1 * 12 + nt) * 2 + t) * 64 + lane) * 8;
            short8v bA = *(const short8v*)pA;
            short8v bB = *(const short8v*)pB;
#pragma unroll
            for (int mt = 0; mt < 2; ++mt) {
                accA[g][mt] = __builtin_amdgcn_mfma_f32_16x16x32_bf16(as_[mt][t], bA, accA[g][mt], 0, 0, 0);
                accB[g][mt] = __builtin_amdgcn_mfma_f32_16x16x32_bf16(ax_[mt][t], bB, accB[g][mt], 0, 0, 0);
            }
        }
    }

    float bi0 = bih[ch], bi1 = bih[64 + ch], bi2 = bih[128 + ch];
    float bh0 = bhh[ch], bh1 = bhh[64 + ch], bh2 = bhh[128 + ch];
    float xo[2][4];
#pragma unroll
    for (int mt = 0; mt < 2; ++mt) {
#pragma unroll
        for (int reg = 0; reg < 4; ++reg) {
            float r  = sigm(accA[0][mt][reg] + bi0 + accB[0][mt][reg] + bh0);
            float zg = sigm(accA[1][mt][reg] + bi1 + accB[1][mt][reg] + bh1);
            float nn = tanhf(accA[2][mt][reg] + bi2 + r * (accB[2][mt][reg] + bh2));
            xo[mt][reg] = (1.0f - zg) * nn + zg * xres[mt][reg];
        }
    }

    if (HAS_T == 0) {
        // last layer: pool directly (fp32 registers -> subgraph2 atomics)
#pragma unroll
        for (int mt = 0; mt < 2; ++mt)
#pragma unroll
            for (int reg = 0; reg < 4; ++reg) {
                int m = mt * 16 + lg * 4 + reg;
                atomicAdd(&sg2[(size_t)n2s2[pnodes[m]] * 64 + ch], xo[mt][reg]);
            }
        return;
    }

    // ---- phase 3: transform (next layer input) ----
#pragma unroll
    for (int mt = 0; mt < 2; ++mt)
#pragma unroll
        for (int reg = 0; reg < 4; ++reg) {
            int m = mt * 16 + lg * 4 + reg;
            u.a[m][ch] = f2b(xo[mt][reg]);
        }
#pragma unroll
    for (int it = 0; it < 2; ++it) {
        int idx = it * 256 + tid;
        int n = idx >> 4, k4 = idx & 15;
        int pn = pnodes[n];
        int z0 = z[pn * 2], z1 = z[pn * 2 + 1];
        float4 e0 = ((const float4*)(zemb_next + (size_t)z0 * 64))[k4];
        float4 e1 = ((const float4*)(zemb_next + (size_t)z1 * 64))[k4];
        ushort4 b;
        b.x = f2b(e0.x + e1.x); b.y = f2b(e0.y + e1.y);
        b.z = f2b(e0.z + e1.z); b.w = f2b(e0.w + e1.w);
        *(ushort4*)&u.a[n][64 + k4 * 4] = b;
    }
    __syncthreads();

    f32x4 tacc[2] = {};
#pragma unroll
    for (int t = 0; t < 4; ++t) {
        const unsigned short* pB = tWpk_next + ((size_t)(w * 4 + t) * 64 + lane) * 8;
        short8v bf = *(const short8v*)pB;
#pragma unroll
        for (int mt = 0; mt < 2; ++mt) {
            int row = mt * 16 + lr, koff = t * 32 + lg * 8;
            short8v af = *(const short8v*)&u.a[row][koff];
            tacc[mt] = __builtin_amdgcn_mfma_f32_16x16x32_bf16(af, bf, tacc[mt], 0, 0, 0);
        }
    }
    float tbc = tb_next[ch];

    // ---- stage output in LDS, then per-row coalesced 16B stores ----
    __shared__ unsigned short outb[32][72];
#pragma unroll
    for (int mt = 0; mt < 2; ++mt)
#pragma unroll
        for (int reg = 0; reg < 4; ++reg) {
            int m = mt * 16 + lg * 4 + reg;
            outb[m][ch] = f2b(tacc[mt][reg] + tbc);
        }
    __syncthreads();
    {
        int r = tid >> 3, q = tid & 7;   // 32 rows x 8 chunks of 16B
        *(float4*)(xb_out + (size_t)pnodes[r] * 64 + q * 8) = *(const float4*)&outb[r][q * 8];
    }
}

// ---- segment-sum pooling via atomics ----
__global__ void pool_kernel(const float* __restrict__ in, const int* __restrict__ idx,
                            float* __restrict__ out, int rows) {
    int i = blockIdx.x * 256 + threadIdx.x;
    if (i >= rows * 64) return;
    int r = i >> 6, c = i & 63;
    atomicAdd(out + (size_t)idx[r] * 64 + c, in[i]);
}

// ---- in-place MLP: buf = relu(buf@W1+b1)@W2+b2, 4 rows per block ----
__global__ __launch_bounds__(256) void mlp_kernel(float* __restrict__ buf,
                                                  const float* __restrict__ W1,
                                                  const float* __restrict__ b1,
                                                  const float* __restrict__ W2,
                                                  const float* __restrict__ b2) {
    __shared__ float in_t[4][64];
    __shared__ float h_t[4][64];
    int tid = threadIdx.x;
    int c = tid & 63, r = tid >> 6;
    int row0 = blockIdx.x * 4;
    in_t[r][c] = buf[(size_t)(row0 + r) * 64 + c];
    __syncthreads();
    float acc = b1[c];
    for (int k = 0; k < 64; ++k) acc = fmaf(in_t[r][k], W1[k * 64 + c], acc);
    h_t[r][c] = fmaxf(acc, 0.0f);
    __syncthreads();
    acc = b2[c];
    for (int k = 0; k < 64; ++k) acc = fmaf(h_t[r][k], W2[k * 64 + c], acc);
    buf[(size_t)(row0 + r) * 64 + c] = acc;
}

// ---- final: g[64,64] -> fc1(elu) -> fc2(elu) -> fc3 -> out[64] ----
__global__ __launch_bounds__(256) void final_kernel(const float* __restrict__ g,
                                                    const float* __restrict__ fc1W, const float* __restrict__ fc1b,
                                                    const float* __restrict__ fc2W, const float* __restrict__ fc2b,
                                                    const float* __restrict__ fc3W, const float* __restrict__ fc3b,
                                                    float* __restrict__ out) {
    __shared__ float gt[64][64];
    __shared__ float h1[64][32];
    __shared__ float h2[64][16];
    int tid = threadIdx.x;
    for (int i = tid; i < 64 * 64; i += 256) gt[i >> 6][i & 63] = g[i];
    __syncthreads();
    for (int i = tid; i < 64 * 32; i += 256) {
        int r = i >> 5, c = i & 31;
        float acc = fc1b[c];
        for (int k = 0; k < 64; ++k) acc = fmaf(gt[r][k], fc1W[k * 32 + c], acc);
        h1[r][c] = elu(acc);
    }
    __syncthreads();
    for (int i = tid; i < 64 * 16; i += 256) {
        int r = i >> 4, c = i & 15;
        float acc = fc2b[c];
        for (int k = 0; k < 32; ++k) acc = fmaf(h1[r][k], fc2W[k * 16 + c], acc);
        h2[r][c] = elu(acc);
    }
    __syncthreads();
    if (tid < 64) {
        float acc = fc3b[0];
        for (int k = 0; k < 16; ++k) acc = fmaf(h2[tid][k], fc3W[k], acc);
        out[tid] = acc;
    }
}

extern "C" void kernel_launch(void* const* d_in, const int* in_sizes, int n_in,
                              void* d_out, int out_size, void* d_ws, size_t ws_size,
                              hipStream_t stream) {
    const int*   z     = (const int*)d_in[0];
    const int*   ei    = (const int*)d_in[1];
    const int*   n2s2  = (const int*)d_in[2];
    const int*   s22s  = (const int*)d_in[3];
    const int*   s2g   = (const int*)d_in[4];
    const float* z_emb = (const float*)d_in[5];
    const float* tW    = (const float*)d_in[6];
    const float* tb    = (const float*)d_in[7];
    const float* convW = (const float*)d_in[8];
    const float* gWih  = (const float*)d_in[9];
    const float* gbih  = (const float*)d_in[10];
    const float* gWhh  = (const float*)d_in[11];
    const float* gbhh  = (const float*)d_in[12];
    const float* epW1  = (const float*)d_in[13];
    const float* epb1  = (const float*)d_in[14];
    const float* epW2  = (const float*)d_in[15];
    const float* epb2  = (const float*)d_in[16];
    const float* npW1  = (const float*)d_in[17];
    const float* npb1  = (const float*)d_in[18];
    const float* npW2  = (const float*)d_in[19];
    const float* npb2  = (const float*)d_in[20];
    const float* fc1W  = (const float*)d_in[21];
    const float* fc1b  = (const float*)d_in[22];
    const float* fc2W  = (const float*)d_in[23];
    const float* fc2b  = (const float*)d_in[24];
    const float* fc3W  = (const float*)d_in[25];
    const float* fc3b  = (const float*)d_in[26];

    const int* srcp = ei;
    const int* dstp = ei + E;

    unsigned short* xbA = (unsigned short*)d_ws;                  // N*64 bf16
    unsigned short* xbB = xbA + (size_t)N * D;                    // N*64 bf16
    float*          WihP = (float*)(xbB + (size_t)N * D);         // L*64*192
    int*            rowptr = (int*)(WihP + L * 64 * 192);         // N+1
    int*            colbuf = rowptr + (N + 1);                    // E
    uintptr_t pal = (uintptr_t)(colbuf + E);
    pal = (pal + 15) & ~(uintptr_t)15;
    unsigned short* Wgpk = (unsigned short*)pal;                  // L*2*12*2*64*8 shorts
    unsigned short* tWpk = Wgpk + (size_t)L * 2 * 12 * 2 * 64 * 8;
    uintptr_t pal2 = (uintptr_t)(tWpk + (size_t)(L - 1) * 4 * 4 * 64 * 8);
    pal2 = (pal2 + 15) & ~(uintptr_t)15;
    unsigned* tmp  = (unsigned*)pal2;                             // CB*NSTR*SCAP2 u32 (9.6 MB)
    int*      bcnt = (int*)(tmp + (size_t)CB * NSTR * SCAP2);     // CB*NSTR*16 ints
    int*      perm = bcnt + (size_t)CB * NSTR * 16;               // N ints
    int*      bh   = perm + N;                                    // CB*NBIN ints
    float*    sg2  = (float*)(bh + (size_t)CB * NBIN);            // NSG2*64
    float*    sg   = sg2 + (size_t)NSG2 * D;                      // NSG*64
    float*    gbuf = sg + (size_t)NSG * D;                        // 64*64

    hipMemsetAsync(bcnt, 0, (size_t)CB * NSTR * 16 * sizeof(int), stream);
    hipMemsetAsync(sg2, 0, (size_t)(NSG2 + NSG + NG) * D * sizeof(float), stream);

    prep_kernel<<<(L * 64 * 192 + 255) / 256, 256, 0, stream>>>(convW, gWih, WihP);
    packg_kernel<<<(L * 2 * 12 * 2 * 64 + 255) / 256, 256, 0, stream>>>(WihP, gWhh, Wgpk);
    packt_kernel<<<((L - 1) * 4 * 4 * 64 + 255) / 256, 256, 0, stream>>>(tW, tWpk);

    csrA_kernel<<<4096, 256, 0, stream>>>(srcp, dstp, bcnt, tmp);
    csrB_kernel<<<CB, 256, 0, stream>>>(tmp, bcnt, rowptr, colbuf);

    degh_kernel<<<CB, 256, 0, stream>>>(rowptr, bh);
    degscan_kernel<<<1, 64, 0, stream>>>(bh);
    degscat_kernel<<<CB, 256, 0, stream>>>(rowptr, bh, perm);

    embed_kernel<<<(N * 16 + 255) / 256, 256, 0, stream>>>(z, z_emb, xbA);

    for (int l = 0; l < L; ++l) {
        const unsigned short* xin = (l & 1) ? xbB : xbA;
        unsigned short*       xout = (l & 1) ? xbA : xbB;
        if (l < L - 1) {
            fused_kernel<1><<<N / 32, 256, 0, stream>>>(
                xin, xout, rowptr, colbuf, perm,
                Wgpk + (size_t)l * 2 * 12 * 2 * 64 * 8,
                gbih + (size_t)l * 192, gbhh + (size_t)l * 192,
                z, z_emb + (size_t)(l + 1) * 100 * 64,
                tWpk + (size_t)l * 4 * 4 * 64 * 8, tb + (size_t)l * 64,
                nullptr, nullptr);
        } else {
            fused_kernel<0><<<N / 32, 256, 0, stream>>>(
                xin, nullptr, rowptr, colbuf, perm,
                Wgpk + (size_t)l * 2 * 12 * 2 * 64 * 8,
                gbih + (size_t)l * 192, gbhh + (size_t)l * 192,
                z, z_emb, tWpk, tb,
                n2s2, sg2);
        }
    }

    // pooling chain (sg2 filled by fused<0> atomics)
    mlp_kernel<<<NSG2 / 4, 256, 0, stream>>>(sg2, epW1, epb1, epW2, epb2);
    pool_kernel<<<(NSG2 * D + 255) / 256, 256, 0, stream>>>(sg2, s22s, sg, NSG2);
    mlp_kernel<<<NSG / 4, 256, 0, stream>>>(sg, npW1, npb1, npW2, npb2);
    pool_kernel<<<(NSG * D + 255) / 256, 256, 0, stream>>>(sg, s2g, gbuf, NSG);
    final_kernel<<<1, 256, 0, stream>>>(gbuf, fc1W, fc1b, fc2W, fc2b, fc3W, fc3b, (float*)d_out);
}

// Round 14
// 456.412 us; speedup vs baseline: 1.0988x; 1.0988x over previous
//
#include <hip/hip_runtime.h>
#include <hip/hip_bf16.h>

constexpr int N    = 100000;
constexpr int E    = 1600000;
constexpr int NSG2 = 20000;
constexpr int NSG  = 2000;
constexpr int NG   = 64;
constexpr int D    = 64;
constexpr int L    = 5;

constexpr int CB    = (N + 255) / 256;    // 391 coarse buckets (256 nodes each)
constexpr int NSTR  = 8;                  // stripes (≈XCDs)
constexpr int SCAP2 = 768;                // per (stripe,bucket) cap: mean 512, +11 sigma
constexpr int NBIN  = 48;                 // degree bins for balance sort

typedef __attribute__((ext_vector_type(8))) short short8v;
typedef __attribute__((ext_vector_type(4))) float f32x4;

__device__ __forceinline__ float sigm(float x) { return 1.0f / (1.0f + expf(-x)); }
__device__ __forceinline__ float elu(float x)  { return x > 0.0f ? x : (expf(x) - 1.0f); }

__device__ __forceinline__ unsigned short f2b(float f) {
    union { float f; unsigned u; } x; x.f = f;
    unsigned r = (x.u + 0x7FFFu + ((x.u >> 16) & 1u)) >> 16;   // RNE
    return (unsigned short)r;
}
__device__ __forceinline__ float b2f(unsigned short h) {
    union { unsigned u; float f; } x; x.u = (unsigned)h << 16;
    return x.f;
}

// ---- WihP[l] = conv_W[l] @ gru_Wih[l]  (64x64 @ 64x192) ----
__global__ __launch_bounds__(256) void prep_kernel(const float* __restrict__ convW,
                                                   const float* __restrict__ Wih,
                                                   float* __restrict__ WihP) {
    int idx = blockIdx.x * 256 + threadIdx.x;   // L*64*192 = 61440
    if (idx >= L * 64 * 192) return;
    int l = idx / (64 * 192);
    int rem = idx % (64 * 192);
    int i = rem / 192, j = rem % 192;
    const float* W  = convW + l * 64 * 64;
    const float* Wi = Wih  + l * 64 * 192;
    float acc = 0.0f;
    for (int t = 0; t < 64; ++t) acc = fmaf(W[i * 64 + t], Wi[t * 192 + j], acc);
    WihP[idx] = acc;
}

// ---- pack GRU weights into bf16 MFMA B-fragments ----
__global__ __launch_bounds__(256) void packg_kernel(const float* __restrict__ WihP,
                                                    const float* __restrict__ gWhh,
                                                    unsigned short* __restrict__ Wgpk) {
    int idx = blockIdx.x * 256 + threadIdx.x;
    if (idx >= L * 2 * 12 * 2 * 64) return;
    int lane = idx & 63;
    int r1 = idx >> 6;
    int t  = r1 & 1;
    int r2 = r1 >> 1;
    int nt = r2 % 12;
    int lm = r2 / 12;             // l*2+mat
    int mat = lm & 1, l = lm >> 1;
    const float* W = mat ? (gWhh + (size_t)l * 64 * 192) : (WihP + (size_t)l * 64 * 192);
    int n  = nt * 16 + (lane & 15);
    int k0 = t * 32 + (lane >> 4) * 8;
    short8v v;
#pragma unroll
    for (int j = 0; j < 8; ++j) v[j] = (short)f2b(W[(k0 + j) * 192 + n]);
    *(short8v*)(Wgpk + (size_t)idx * 8) = v;
}

// ---- pack transform weights ----
__global__ __launch_bounds__(256) void packt_kernel(const float* __restrict__ tW,
                                                    unsigned short* __restrict__ tWpk) {
    int idx = blockIdx.x * 256 + threadIdx.x;
    if (idx >= (L - 1) * 4 * 4 * 64) return;
    int lane = idx & 63;
    int r1 = idx >> 6;
    int t  = r1 & 3;
    int r2 = r1 >> 2;
    int nt = r2 & 3;
    int lm = r2 >> 2;
    const float* W = tW + (size_t)lm * 128 * 64;
    int n  = nt * 16 + (lane & 15);
    int k0 = t * 32 + (lane >> 4) * 8;
    short8v v;
#pragma unroll
    for (int j = 0; j < 8; ++j) v[j] = (short)f2b(W[(k0 + j) * 64 + n]);
    *(short8v*)(tWpk + (size_t)idx * 8) = v;
}

// ---- CSR A: scatter into 391 coarse buckets x 8 stripes ----
__global__ void csrA_kernel(const int* __restrict__ src, const int* __restrict__ dst,
                            int* __restrict__ bcnt, unsigned* __restrict__ tmp) {
    int stripe = blockIdx.x & (NSTR - 1);
    for (int e = blockIdx.x * blockDim.x + threadIdx.x; e < E; e += gridDim.x * blockDim.x) {
        int d = dst[e];
        int cell = stripe * CB + (d >> 8);
        int pos = atomicAdd(&bcnt[cell * 16], 1);   // 64B-strided counters
        if (pos < SCAP2)
            tmp[(size_t)cell * SCAP2 + pos] = ((unsigned)(d & 255) << 17) | (unsigned)src[e];
    }
}

// ---- CSR B: one block per coarse bucket; hist(256) -> scan -> rowptr + sorted col ----
__global__ __launch_bounds__(256) void csrB_kernel(const unsigned* __restrict__ tmp,
                                                   const int* __restrict__ bcnt,
                                                   int* __restrict__ rowptr,
                                                   int* __restrict__ col) {
    __shared__ int hist[256];
    __shared__ int scanb[256];
    __shared__ int cur[256];
    __shared__ int scnt[NSTR];
    __shared__ int red[4];
    int b = blockIdx.x, t = threadIdx.x;
    int lane = t & 63, wid = t >> 6;

    int myb = 0;
    for (int cb = t; cb < b; cb += 256) {
        int tot = 0;
#pragma unroll
        for (int s = 0; s < NSTR; ++s) tot += min(bcnt[(s * CB + cb) * 16], SCAP2);
        myb += tot;
    }
#pragma unroll
    for (int off = 32; off > 0; off >>= 1) myb += __shfl_down(myb, off, 64);
    if (lane == 0) red[wid] = myb;
    if (t < NSTR) scnt[t] = min(bcnt[(t * CB + b) * 16], SCAP2);
    hist[t] = 0;
    __syncthreads();
    int base = red[0] + red[1] + red[2] + red[3];

    for (int s = 0; s < NSTR; ++s)
        for (int i = t; i < scnt[s]; i += 256)
            atomicAdd(&hist[tmp[((size_t)s * CB + b) * SCAP2 + i] >> 17], 1);
    __syncthreads();

    scanb[t] = hist[t];
    __syncthreads();
    for (int off = 1; off < 256; off <<= 1) {
        int v = (t >= off) ? scanb[t - off] : 0;
        __syncthreads();
        scanb[t] += v;
        __syncthreads();
    }
    int excl = scanb[t] - hist[t];
    int node = b * 256 + t;
    if (node < N) rowptr[node] = base + excl;
    if (b == CB - 1 && t == 255) rowptr[N] = base + scanb[255];
    cur[t] = base + excl;
    __syncthreads();

    for (int s = 0; s < NSTR; ++s)
        for (int i = t; i < scnt[s]; i += 256) {
            unsigned rec = tmp[((size_t)s * CB + b) * SCAP2 + i];
            int pos = atomicAdd(&cur[rec >> 17], 1);
            col[pos] = (int)(rec & 0x1FFFFu);
        }
}

// ---- degree-balance permutation: counting sort by degree (grid-parallel) ----
__global__ __launch_bounds__(256) void degh_kernel(const int* __restrict__ rowptr,
                                                   int* __restrict__ bh) {
    __shared__ int h[NBIN];
    int b = blockIdx.x, t = threadIdx.x;
    if (t < NBIN) h[t] = 0;
    __syncthreads();
    int node = b * 256 + t;
    if (node < N) {
        int d = rowptr[node + 1] - rowptr[node];
        atomicAdd(&h[min(d, NBIN - 1)], 1);
    }
    __syncthreads();
    if (t < NBIN) bh[b * NBIN + t] = h[t];
}

// one block per bin: parallel exclusive scan over CB buckets
__global__ __launch_bounds__(512) void degscan_par_kernel(int* __restrict__ bh,
                                                          int* __restrict__ bintot) {
    __shared__ int sh[512];
    int bin = blockIdx.x, t = threadIdx.x;
    int v = (t < CB) ? bh[t * NBIN + bin] : 0;
    sh[t] = v;
    __syncthreads();
    for (int off = 1; off < 512; off <<= 1) {
        int u = (t >= off) ? sh[t - off] : 0;
        __syncthreads();
        sh[t] += u;
        __syncthreads();
    }
    if (t < CB) bh[t * NBIN + bin] = sh[t] - v;   // exclusive within bin
    if (t == 511) bintot[bin] = sh[511];
}

__global__ __launch_bounds__(64) void binbase_kernel(int* __restrict__ bintot) {
    __shared__ int sh[NBIN];
    int t = threadIdx.x;
    int v = (t < NBIN) ? bintot[t] : 0;
    if (t < NBIN) sh[t] = v;
    __syncthreads();
    if (t == 0) {
        int r = 0;
        for (int j = 0; j < NBIN; ++j) { int x = sh[j]; sh[j] = r; r += x; }
    }
    __syncthreads();
    if (t < NBIN) bintot[t] = sh[t];   // now exclusive bin base
}

__global__ __launch_bounds__(256) void degscat_kernel(const int* __restrict__ rowptr,
                                                      const int* __restrict__ bh,
                                                      const int* __restrict__ binbase,
                                                      int* __restrict__ perm) {
    __shared__ int cur[NBIN];
    int b = blockIdx.x, t = threadIdx.x;
    if (t < NBIN) cur[t] = bh[b * NBIN + t] + binbase[t];
    __syncthreads();
    int node = b * 256 + t;
    if (node < N) {
        int d = rowptr[node + 1] - rowptr[node];
        int pos = atomicAdd(&cur[min(d, NBIN - 1)], 1);
        perm[pos] = node;
    }
}

// ---- x0 = z_emb[0][z].sum(1) -> bf16 ----
__global__ __launch_bounds__(256) void embed_kernel(const int* __restrict__ z,
                                                    const float* __restrict__ zemb0,
                                                    unsigned short* __restrict__ xb) {
    int idx = blockIdx.x * 256 + threadIdx.x;  // N*16 float4 units
    if (idx >= N * 16) return;
    int n = idx >> 4, k4 = idx & 15;
    float4 e0 = ((const float4*)(zemb0 + (size_t)z[n * 2] * 64))[k4];
    float4 e1 = ((const float4*)(zemb0 + (size_t)z[n * 2 + 1] * 64))[k4];
    ushort4 b; b.x = f2b(e0.x + e1.x); b.y = f2b(e0.y + e1.y);
    b.z = f2b(e0.z + e1.z); b.w = f2b(e0.w + e1.w);
    ((ushort4*)xb)[idx] = b;
}

// ---- fused layer (degree-sorted node order via perm) ----
template<int HAS_T>
__global__ __launch_bounds__(256) void fused_kernel(const unsigned short* __restrict__ xb_in,
                                                    unsigned short* __restrict__ xb_out,
                                                    const int* __restrict__ rowptr,
                                                    const int* __restrict__ col,
                                                    const int* __restrict__ perm,
                                                    const unsigned short* __restrict__ Wgpk_l,
                                                    const float* __restrict__ bih,
                                                    const float* __restrict__ bhh,
                                                    const int* __restrict__ z,
                                                    const float* __restrict__ zemb_next,
                                                    const unsigned short* __restrict__ tWpk_next,
                                                    const float* __restrict__ tb_next,
                                                    const int* __restrict__ n2s2,
                                                    float* __restrict__ sg2) {
    __shared__ union {
        struct { unsigned short s[32][72]; unsigned short x[32][72]; } p1;  // 9216 B
        unsigned short a[32][136];                                          // 8704 B
    } u;
    __shared__ int pnodes[32];
    int tid = threadIdx.x;
    int node0 = blockIdx.x * 32;
    int lane = tid & 63, w = tid >> 6;

    if (tid < 32) pnodes[tid] = perm[node0 + tid];
    __syncthreads();

    // ---- phase 1: aggregate, 8/4/2/1-deep pipelined gather (equal-degree nodes) ----
    {
        int g8 = lane >> 3, cj = lane & 7;
        int nl = w * 8 + g8;
        int node = pnodes[nl];
        float4 ownx = ((const float4*)(xb_in + (size_t)node * 64))[cj];
        int beg = rowptr[node], end = rowptr[node + 1];
        float a[8] = {};
        const unsigned short* __restrict__ xbc = xb_in + cj * 8;
        int i = beg;
        for (; i + 8 <= end; i += 8) {
            int u0 = col[i],     u1 = col[i + 1], u2 = col[i + 2], u3 = col[i + 3];
            int u4 = col[i + 4], u5 = col[i + 5], u6 = col[i + 6], u7 = col[i + 7];
            short8v v0 = *(const short8v*)(xbc + (size_t)u0 * 64);
            short8v v1 = *(const short8v*)(xbc + (size_t)u1 * 64);
            short8v v2 = *(const short8v*)(xbc + (size_t)u2 * 64);
            short8v v3 = *(const short8v*)(xbc + (size_t)u3 * 64);
            short8v v4 = *(const short8v*)(xbc + (size_t)u4 * 64);
            short8v v5 = *(const short8v*)(xbc + (size_t)u5 * 64);
            short8v v6 = *(const short8v*)(xbc + (size_t)u6 * 64);
            short8v v7 = *(const short8v*)(xbc + (size_t)u7 * 64);
#pragma unroll
            for (int j = 0; j < 8; ++j)
                a[j] += ((b2f((unsigned short)v0[j]) + b2f((unsigned short)v1[j])) +
                         (b2f((unsigned short)v2[j]) + b2f((unsigned short)v3[j]))) +
                        ((b2f((unsigned short)v4[j]) + b2f((unsigned short)v5[j])) +
                         (b2f((unsigned short)v6[j]) + b2f((unsigned short)v7[j])));
        }
        for (; i + 4 <= end; i += 4) {
            int u0 = col[i], u1 = col[i + 1], u2 = col[i + 2], u3 = col[i + 3];
            short8v v0 = *(const short8v*)(xbc + (size_t)u0 * 64);
            short8v v1 = *(const short8v*)(xbc + (size_t)u1 * 64);
            short8v v2 = *(const short8v*)(xbc + (size_t)u2 * 64);
            short8v v3 = *(const short8v*)(xbc + (size_t)u3 * 64);
#pragma unroll
            for (int j = 0; j < 8; ++j)
                a[j] += (b2f((unsigned short)v0[j]) + b2f((unsigned short)v1[j])) +
                        (b2f((unsigned short)v2[j]) + b2f((unsigned short)v3[j]));
        }
        for (; i + 2 <= end; i += 2) {
            int u0 = col[i], u1 = col[i + 1];
            short8v v0 = *(const short8v*)(xbc + (size_t)u0 * 64);
            short8v v1 = *(const short8v*)(xbc + (size_t)u1 * 64);
#pragma unroll
            for (int j = 0; j < 8; ++j)
                a[j] += b2f((unsigned short)v0[j]) + b2f((unsigned short)v1[j]);
        }
        if (i < end) {
            short8v v = *(const short8v*)(xbc + (size_t)col[i] * 64);
#pragma unroll
            for (int j = 0; j < 8; ++j) a[j] += b2f((unsigned short)v[j]);
        }
        short8v r;
#pragma unroll
        for (int j = 0; j < 8; ++j) r[j] = (short)f2b(a[j]);
        *(short8v*)&u.p1.s[nl][cj * 8] = r;
        *(float4*)&u.p1.x[nl][cj * 8] = ownx;
    }
    __syncthreads();

    // ---- phase 2: GRU MFMA ----
    int lr = lane & 15, lg = lane >> 4;
    int ch = w * 16 + lr;
    short8v as_[2][2], ax_[2][2];
#pragma unroll
    for (int mt = 0; mt < 2; ++mt)
#pragma unroll
        for (int t = 0; t < 2; ++t) {
            int row = mt * 16 + lr, koff = t * 32 + lg * 8;
            as_[mt][t] = *(const short8v*)&u.p1.s[row][koff];
            ax_[mt][t] = *(const short8v*)&u.p1.x[row][koff];
        }
    float xres[2][4];
#pragma unroll
    for (int mt = 0; mt < 2; ++mt)
#pragma unroll
        for (int reg = 0; reg < 4; ++reg)
            xres[mt][reg] = b2f(u.p1.x[mt * 16 + lg * 4 + reg][ch]);
    if (HAS_T) __syncthreads();   // all p1 reads done before a-tile aliasing writes

    f32x4 accA[3][2] = {};
    f32x4 accB[3][2] = {};
#pragma unroll
    for (int g = 0; g < 3; ++g) {
        int nt = g * 4 + w;
#pragma unroll
        for (int t = 0; t < 2; ++t) {
            const unsigned short* pA = Wgpk_l + ((size_t)((0 * 12 + nt) * 2 + t) * 64 + lane) * 8;
            const unsigned short* pB = Wgpk_l + ((size_t)((1 * 12 + nt) * 2 + t) * 64 + lane) * 8;
            short8v bA = *(const short8v*)pA;
            short8v bB = *(const short8v*)pB;
#pragma unroll
            for (int mt = 0; mt < 2; ++mt) {
                accA[g][mt] = __builtin_amdgcn_mfma_f32_16x16x32_bf16(as_[mt][t], bA, accA[g][mt], 0, 0, 0);
                accB[g][mt] = __builtin_amdgcn_mfma_f32_16x16x32_bf16(ax_[mt][t], bB, accB[g][mt], 0, 0, 0);
            }
        }
    }

    float bi0 = bih[ch], bi1 = bih[64 + ch], bi2 = bih[128 + ch];
    float bh0 = bhh[ch], bh1 = bhh[64 + ch], bh2 = bhh[128 + ch];
    float xo[2][4];
#pragma unroll
    for (int mt = 0; mt < 2; ++mt) {
#pragma unroll
        for (int reg = 0; reg < 4; ++reg) {
            float r  = sigm(accA[0][mt][reg] + bi0 + accB[0][mt][reg] + bh0);
            float zg = sigm(accA[1][mt][reg] + bi1 + accB[1][mt][reg] + bh1);
            float nn = tanhf(accA[2][mt][reg] + bi2 + r * (accB[2][mt][reg] + bh2));
            xo[mt][reg] = (1.0f - zg) * nn + zg * xres[mt][reg];
        }
    }

    if (HAS_T == 0) {
        // last layer: pool directly (fp32 registers -> subgraph2 atomics)
#pragma unroll
        for (int mt = 0; mt < 2; ++mt)
#pragma unroll
            for (int reg = 0; reg < 4; ++reg) {
                int m = mt * 16 + lg * 4 + reg;
                atomicAdd(&sg2[(size_t)n2s2[pnodes[m]] * 64 + ch], xo[mt][reg]);
            }
        return;
    }

    // ---- phase 3: transform (next layer input) ----
#pragma unroll
    for (int mt = 0; mt < 2; ++mt)
#pragma unroll
        for (int reg = 0; reg < 4; ++reg) {
            int m = mt * 16 + lg * 4 + reg;
            u.a[m][ch] = f2b(xo[mt][reg]);
        }
#pragma unroll
    for (int it = 0; it < 2; ++it) {
        int idx = it * 256 + tid;
        int n = idx >> 4, k4 = idx & 15;
        int pn = pnodes[n];
        int z0 = z[pn * 2], z1 = z[pn * 2 + 1];
        float4 e0 = ((const float4*)(zemb_next + (size_t)z0 * 64))[k4];
        float4 e1 = ((const float4*)(zemb_next + (size_t)z1 * 64))[k4];
        ushort4 b;
        b.x = f2b(e0.x + e1.x); b.y = f2b(e0.y + e1.y);
        b.z = f2b(e0.z + e1.z); b.w = f2b(e0.w + e1.w);
        *(ushort4*)&u.a[n][64 + k4 * 4] = b;
    }
    __syncthreads();

    f32x4 tacc[2] = {};
#pragma unroll
    for (int t = 0; t < 4; ++t) {
        const unsigned short* pB = tWpk_next + ((size_t)(w * 4 + t) * 64 + lane) * 8;
        short8v bf = *(const short8v*)pB;
#pragma unroll
        for (int mt = 0; mt < 2; ++mt) {
            int row = mt * 16 + lr, koff = t * 32 + lg * 8;
            short8v af = *(const short8v*)&u.a[row][koff];
            tacc[mt] = __builtin_amdgcn_mfma_f32_16x16x32_bf16(af, bf, tacc[mt], 0, 0, 0);
        }
    }
    float tbc = tb_next[ch];

    // ---- stage output in LDS, then per-row coalesced 16B stores ----
    __shared__ unsigned short outb[32][72];
#pragma unroll
    for (int mt = 0; mt < 2; ++mt)
#pragma unroll
        for (int reg = 0; reg < 4; ++reg) {
            int m = mt * 16 + lg * 4 + reg;
            outb[m][ch] = f2b(tacc[mt][reg] + tbc);
        }
    __syncthreads();
    {
        int r = tid >> 3, q = tid & 7;   // 32 rows x 8 chunks of 16B
        *(float4*)(xb_out + (size_t)pnodes[r] * 64 + q * 8) = *(const float4*)&outb[r][q * 8];
    }
}

// ---- segment-sum pooling via atomics ----
__global__ void pool_kernel(const float* __restrict__ in, const int* __restrict__ idx,
                            float* __restrict__ out, int rows) {
    int i = blockIdx.x * 256 + threadIdx.x;
    if (i >= rows * 64) return;
    int r = i >> 6, c = i & 63;
    atomicAdd(out + (size_t)idx[r] * 64 + c, in[i]);
}

// ---- in-place MLP: buf = relu(buf@W1+b1)@W2+b2, 4 rows per block ----
__global__ __launch_bounds__(256) void mlp_kernel(float* __restrict__ buf,
                                                  const float* __restrict__ W1,
                                                  const float* __restrict__ b1,
                                                  const float* __restrict__ W2,
                                                  const float* __restrict__ b2) {
    __shared__ float in_t[4][64];
    __shared__ float h_t[4][64];
    int tid = threadIdx.x;
    int c = tid & 63, r = tid >> 6;
    int row0 = blockIdx.x * 4;
    in_t[r][c] = buf[(size_t)(row0 + r) * 64 + c];
    __syncthreads();
    float acc = b1[c];
    for (int k = 0; k < 64; ++k) acc = fmaf(in_t[r][k], W1[k * 64 + c], acc);
    h_t[r][c] = fmaxf(acc, 0.0f);
    __syncthreads();
    acc = b2[c];
    for (int k = 0; k < 64; ++k) acc = fmaf(h_t[r][k], W2[k * 64 + c], acc);
    buf[(size_t)(row0 + r) * 64 + c] = acc;
}

// ---- final: g[64,64] -> fc1(elu) -> fc2(elu) -> fc3 -> out[64] ----
__global__ __launch_bounds__(256) void final_kernel(const float* __restrict__ g,
                                                    const float* __restrict__ fc1W, const float* __restrict__ fc1b,
                                                    const float* __restrict__ fc2W, const float* __restrict__ fc2b,
                                                    const float* __restrict__ fc3W, const float* __restrict__ fc3b,
                                                    float* __restrict__ out) {
    __shared__ float gt[64][64];
    __shared__ float h1[64][32];
    __shared__ float h2[64][16];
    int tid = threadIdx.x;
    for (int i = tid; i < 64 * 64; i += 256) gt[i >> 6][i & 63] = g[i];
    __syncthreads();
    for (int i = tid; i < 64 * 32; i += 256) {
        int r = i >> 5, c = i & 31;
        float acc = fc1b[c];
        for (int k = 0; k < 64; ++k) acc = fmaf(gt[r][k], fc1W[k * 32 + c], acc);
        h1[r][c] = elu(acc);
    }
    __syncthreads();
    for (int i = tid; i < 64 * 16; i += 256) {
        int r = i >> 4, c = i & 15;
        float acc = fc2b[c];
        for (int k = 0; k < 32; ++k) acc = fmaf(h1[r][k], fc2W[k * 16 + c], acc);
        h2[r][c] = elu(acc);
    }
    __syncthreads();
    if (tid < 64) {
        float acc = fc3b[0];
        for (int k = 0; k < 16; ++k) acc = fmaf(h2[tid][k], fc3W[k], acc);
        out[tid] = acc;
    }
}

extern "C" void kernel_launch(void* const* d_in, const int* in_sizes, int n_in,
                              void* d_out, int out_size, void* d_ws, size_t ws_size,
                              hipStream_t stream) {
    const int*   z     = (const int*)d_in[0];
    const int*   ei    = (const int*)d_in[1];
    const int*   n2s2  = (const int*)d_in[2];
    const int*   s22s  = (const int*)d_in[3];
    const int*   s2g   = (const int*)d_in[4];
    const float* z_emb = (const float*)d_in[5];
    const float* tW    = (const float*)d_in[6];
    const float* tb    = (const float*)d_in[7];
    const float* convW = (const float*)d_in[8];
    const float* gWih  = (const float*)d_in[9];
    const float* gbih  = (const float*)d_in[10];
    const float* gWhh  = (const float*)d_in[11];
    const float* gbhh  = (const float*)d_in[12];
    const float* epW1  = (const float*)d_in[13];
    const float* epb1  = (const float*)d_in[14];
    const float* epW2  = (const float*)d_in[15];
    const float* epb2  = (const float*)d_in[16];
    const float* npW1  = (const float*)d_in[17];
    const float* npb1  = (const float*)d_in[18];
    const float* npW2  = (const float*)d_in[19];
    const float* npb2  = (const float*)d_in[20];
    const float* fc1W  = (const float*)d_in[21];
    const float* fc1b  = (const float*)d_in[22];
    const float* fc2W  = (const float*)d_in[23];
    const float* fc2b  = (const float*)d_in[24];
    const float* fc3W  = (const float*)d_in[25];
    const float* fc3b  = (const float*)d_in[26];

    const int* srcp = ei;
    const int* dstp = ei + E;

    unsigned short* xbA = (unsigned short*)d_ws;                  // N*64 bf16
    unsigned short* xbB = xbA + (size_t)N * D;                    // N*64 bf16
    float*          WihP = (float*)(xbB + (size_t)N * D);         // L*64*192
    int*            rowptr = (int*)(WihP + L * 64 * 192);         // N+1
    int*            colbuf = rowptr + (N + 1);                    // E
    uintptr_t pal = (uintptr_t)(colbuf + E);
    pal = (pal + 15) & ~(uintptr_t)15;
    unsigned short* Wgpk = (unsigned short*)pal;                  // L*2*12*2*64*8 shorts
    unsigned short* tWpk = Wgpk + (size_t)L * 2 * 12 * 2 * 64 * 8;
    uintptr_t pal2 = (uintptr_t)(tWpk + (size_t)(L - 1) * 4 * 4 * 64 * 8);
    pal2 = (pal2 + 15) & ~(uintptr_t)15;
    unsigned* tmp  = (unsigned*)pal2;                             // CB*NSTR*SCAP2 u32 (9.6 MB)
    int*      bcnt = (int*)(tmp + (size_t)CB * NSTR * SCAP2);     // CB*NSTR*16 ints
    int*      perm = bcnt + (size_t)CB * NSTR * 16;               // N ints
    int*      bh   = perm + N;                                    // CB*NBIN ints
    int*      bintot = bh + (size_t)CB * NBIN;                    // NBIN ints
    float*    sg2  = (float*)(bintot + NBIN);                     // NSG2*64
    float*    sg   = sg2 + (size_t)NSG2 * D;                      // NSG*64
    float*    gbuf = sg + (size_t)NSG * D;                        // 64*64

    hipMemsetAsync(bcnt, 0, (size_t)CB * NSTR * 16 * sizeof(int), stream);
    hipMemsetAsync(sg2, 0, (size_t)(NSG2 + NSG + NG) * D * sizeof(float), stream);

    prep_kernel<<<(L * 64 * 192 + 255) / 256, 256, 0, stream>>>(convW, gWih, WihP);
    packg_kernel<<<(L * 2 * 12 * 2 * 64 + 255) / 256, 256, 0, stream>>>(WihP, gWhh, Wgpk);
    packt_kernel<<<((L - 1) * 4 * 4 * 64 + 255) / 256, 256, 0, stream>>>(tW, tWpk);

    csrA_kernel<<<4096, 256, 0, stream>>>(srcp, dstp, bcnt, tmp);
    csrB_kernel<<<CB, 256, 0, stream>>>(tmp, bcnt, rowptr, colbuf);

    degh_kernel<<<CB, 256, 0, stream>>>(rowptr, bh);
    degscan_par_kernel<<<NBIN, 512, 0, stream>>>(bh, bintot);
    binbase_kernel<<<1, 64, 0, stream>>>(bintot);
    degscat_kernel<<<CB, 256, 0, stream>>>(rowptr, bh, bintot, perm);

    embed_kernel<<<(N * 16 + 255) / 256, 256, 0, stream>>>(z, z_emb, xbA);

    for (int l = 0; l < L; ++l) {
        const unsigned short* xin = (l & 1) ? xbB : xbA;
        unsigned short*       xout = (l & 1) ? xbA : xbB;
        if (l < L - 1) {
            fused_kernel<1><<<N / 32, 256, 0, stream>>>(
                xin, xout, rowptr, colbuf, perm,
                Wgpk + (size_t)l * 2 * 12 * 2 * 64 * 8,
                gbih + (size_t)l * 192, gbhh + (size_t)l * 192,
                z, z_emb + (size_t)(l + 1) * 100 * 64,
                tWpk + (size_t)l * 4 * 4 * 64 * 8, tb + (size_t)l * 64,
                nullptr, nullptr);
        } else {
            fused_kernel<0><<<N / 32, 256, 0, stream>>>(
                xin, nullptr, rowptr, colbuf, perm,
                Wgpk + (size_t)l * 2 * 12 * 2 * 64 * 8,
                gbih + (size_t)l * 192, gbhh + (size_t)l * 192,
                z, z_emb, tWpk, tb,
                n2s2, sg2);
        }
    }

    // pooling chain (sg2 filled by fused<0> atomics)
    mlp_kernel<<<NSG2 / 4, 256, 0, stream>>>(sg2, epW1, epb1, epW2, epb2);
    pool_kernel<<<(NSG2 * D + 255) / 256, 256, 0, stream>>>(sg2, s22s, sg, NSG2);
    mlp_kernel<<<NSG / 4, 256, 0, stream>>>(sg, npW1, npb1, npW2, npb2);
    pool_kernel<<<(NSG * D + 255) / 256, 256, 0, stream>>>(sg, s2g, gbuf, NSG);
    final_kernel<<<1, 256, 0, stream>>>(gbuf, fc1W, fc1b, fc2W, fc2b, fc3W, fc3b, (float*)d_out);
}